// Round 3
// baseline (593.662 us; speedup 1.0000x reference)
//
#include <hip/hip_runtime.h>
#include <math.h>

#define B_   32
#define H_   32
#define HKV  8
#define G_   4
#define D_   128
#define BS_  128
#define NB_  16
#define CH_  2             // cache blocks per chunk
#define NCH  (NB_ / CH_)   // 8 chunks per sequence
#define CP_  (CH_ * BS_)   // 256 positions per chunk
#define NPART 32           // per (b,kh): 8 chunks x 4 waves, each wave = 64 rows
#define PART_STRIDE (G_ + G_ + G_ * D_)   // m[4] l[4] o[4][128] = 520 floats

typedef float v4f __attribute__((ext_vector_type(4)));

constexpr float SCALE_ = 0.08838834764831845f;  // 1/sqrt(128)

__device__ __forceinline__ float dot4(const float4 a, const float4 b) {
    return a.x * b.x + a.y * b.y + a.z * b.z + a.w * b.w;
}

// Non-temporal 16B load: K/V are streamed exactly once.
__device__ __forceinline__ float4 ntload4(const float* p) {
    v4f t = __builtin_nontemporal_load((const v4f*)p);
    return make_float4(t.x, t.y, t.z, t.w);
}

// Q fragment load with scale folded in.
__device__ __forceinline__ float4 ldq(const float* p) {
    float4 v = *(const float4*)p;
    return make_float4(v.x * SCALE_, v.y * SCALE_, v.z * SCALE_, v.w * SCALE_);
}

// ---------------------------------------------------------------------------
// Kernel 1: partial attention. Grid 2048 = B*HKV*NCH, 256 threads (4 waves).
// BARRIER-FREE: each wave owns an independent 64-row window and produces its
// own (m, l, o) partial — per-wave softmax lives entirely in registers
// (in-lane reduce over 8 statically-indexed rows + shfl_xor 8/16/32).
// The only LDS use is the per-wave p matrix handed from Phase A lanes to
// Phase C lanes; intra-wave DS ordering is enforced with lgkmcnt(0) +
// sched_barrier(0) (no s_barrier anywhere).
//
// INPUT-PURE: caches never written; the new decode token's K/V row is
// substituted in-register at row ctx-1. Bias never read: active rows have
// bias == 0.0, inactive rows get score -inf (exp -> 0) directly.
// ---------------------------------------------------------------------------
__global__ __launch_bounds__(256) void partial_attn(
    const float* __restrict__ query,
    const float* __restrict__ knew,
    const float* __restrict__ vnew,
    const float* __restrict__ kcache,
    const float* __restrict__ vcache,
    const int* __restrict__ block_list,
    const int* __restrict__ bidx, const int* __restrict__ boff,
    float* __restrict__ ws)
{
    __shared__ float sc[4][64][G_];      // 4 KB: per-wave p values

    const int tid  = threadIdx.x;
    const int w    = tid >> 6;
    const int lane = tid & 63;
    const int bx   = blockIdx.x;
    const int ch   = bx & (NCH - 1);
    const int kh   = (bx >> 3) & 7;
    const int b    = bx >> 6;

    // ---- recover ctx: which seq-local block holds the new token ----
    const int my_bi = bidx[b];
    int jstar = 0;
#pragma unroll
    for (int jj = 0; jj < NB_; ++jj)
        if (block_list[b * NB_ + jj] == my_bi) jstar = jj;
    const int ctx = jstar * BS_ + boff[b] + 1;   // tokens in this sequence

    float* wp = ws + (size_t)(bx * 4 + w) * PART_STRIDE;
    const int chunk_start = ch * CP_;
    if (ctx <= chunk_start) {                    // fully masked chunk
        if (lane == 0)
            *(float4*)wp = make_float4(-INFINITY, -INFINITY, -INFINITY, -INFINITY);
        return;
    }

    // wave -> block and 64-row window
    const int j  = ch * CH_ + (w >> 1);
    const int cb = block_list[b * NB_ + j];
    const int sb_base = (w & 1) * 64;
    const float* kb = kcache + ((size_t)cb * BS_ * HKV + kh) * D_;
    const float* vb = vcache + ((size_t)cb * BS_ * HKV + kh) * D_;
    const int wave_start = j * BS_ + sb_base;                 // abs pos of row 0
    const int valid_rows = min(64, max(0, ctx - wave_start)); // rows to process
    if (valid_rows <= 0) {                       // inactive wave: empty partial
        if (lane == 0)
            *(float4*)wp = make_float4(-INFINITY, -INFINITY, -INFINITY, -INFINITY);
        return;                                  // barrier-free: safe to exit
    }
    const int newrow = (ctx - 1) - wave_start;   // row of new token (may be OOR)
    const float* knew_h = knew + ((size_t)b * HKV + kh) * D_;
    const float* vnew_h = vnew + ((size_t)b * HKV + kh) * D_;

    const int lr = lane >> 3;    // row subgroup 0..7
    const int lc = lane & 7;     // dim subgroup
    const int doff = lc * 4;

    // ---- Q fragments straight from global (L1/L2-cached, 2 KB/wave) ----
    const float* qh = query + (size_t)b * (H_ * D_) + (size_t)(kh * G_) * D_;
    const float4 q00 = ldq(qh + 0*D_ +  0 + doff);
    const float4 q01 = ldq(qh + 0*D_ + 32 + doff);
    const float4 q02 = ldq(qh + 0*D_ + 64 + doff);
    const float4 q03 = ldq(qh + 0*D_ + 96 + doff);
    const float4 q10 = ldq(qh + 1*D_ +  0 + doff);
    const float4 q11 = ldq(qh + 1*D_ + 32 + doff);
    const float4 q12 = ldq(qh + 1*D_ + 64 + doff);
    const float4 q13 = ldq(qh + 1*D_ + 96 + doff);
    const float4 q20 = ldq(qh + 2*D_ +  0 + doff);
    const float4 q21 = ldq(qh + 2*D_ + 32 + doff);
    const float4 q22 = ldq(qh + 2*D_ + 64 + doff);
    const float4 q23 = ldq(qh + 2*D_ + 96 + doff);
    const float4 q30 = ldq(qh + 3*D_ +  0 + doff);
    const float4 q31 = ldq(qh + 3*D_ + 32 + doff);
    const float4 q32 = ldq(qh + 3*D_ + 64 + doff);
    const float4 q33 = ldq(qh + 3*D_ + 96 + doff);

    // ---- Phase A: scores, fixed 8 iterations, depth-1 pipeline ----
    // After the 4/2/1 butterfly every lane holds the full dot for row
    // i*8+lr, so each lane statically keeps all 8 rows x 4 g in sreg[].
    float4 sreg[8];
    float4 c0, c1, c2, c3;
    {
        const int r = lr;
        if (r < valid_rows) {
            const float* kr = (r == newrow)
                ? (knew_h + doff)
                : (kb + (size_t)(sb_base + r) * (HKV * D_) + doff);
            c0 = ntload4(kr);      c1 = ntload4(kr + 32);
            c2 = ntload4(kr + 64); c3 = ntload4(kr + 96);
        } else {
            c0 = c1 = c2 = c3 = make_float4(0, 0, 0, 0);
        }
    }
#pragma unroll
    for (int i = 0; i < 8; ++i) {
        float4 n0, n1, n2, n3;
        n0 = n1 = n2 = n3 = make_float4(0, 0, 0, 0);
        const int rn = ((i + 1) << 3) + lr;
        if (rn < valid_rows) {     // false automatically for i == 7
            const float* kr = (rn == newrow)
                ? (knew_h + doff)
                : (kb + (size_t)(sb_base + rn) * (HKV * D_) + doff);
            n0 = ntload4(kr);      n1 = ntload4(kr + 32);
            n2 = ntload4(kr + 64); n3 = ntload4(kr + 96);
        }
        float d0 = dot4(c0,q00) + dot4(c1,q01) + dot4(c2,q02) + dot4(c3,q03);
        float d1 = dot4(c0,q10) + dot4(c1,q11) + dot4(c2,q12) + dot4(c3,q13);
        float d2 = dot4(c0,q20) + dot4(c1,q21) + dot4(c2,q22) + dot4(c3,q23);
        float d3 = dot4(c0,q30) + dot4(c1,q31) + dot4(c2,q32) + dot4(c3,q33);
#pragma unroll
        for (int msk = 4; msk >= 1; msk >>= 1) {
            d0 += __shfl_xor(d0, msk, 64);
            d1 += __shfl_xor(d1, msk, 64);
            d2 += __shfl_xor(d2, msk, 64);
            d3 += __shfl_xor(d3, msk, 64);
        }
        const bool act = ((i << 3) + lr) < valid_rows;
        sreg[i] = act ? make_float4(d0, d1, d2, d3)
                      : make_float4(-INFINITY, -INFINITY, -INFINITY, -INFINITY);
        c0 = n0; c1 = n1; c2 = n2; c3 = n3;
    }

    // ---- Phase C prologue: issue first V loads now, latency hides under
    //      the softmax VALU work below ----
    const int half = lane >> 5;
    const int l5   = lane & 31;
    const int dd   = l5 * 4;
    const int itC  = min(32, (valid_rows + 1) >> 1);   // >= 1 here
    float4 cv;
    {
        const int r0 = half;
        const float* vr = (r0 == newrow)
            ? (vnew_h + dd)
            : (vb + (size_t)(sb_base + r0) * (HKV * D_) + dd);
        cv = ntload4(vr);
    }

    // ---- Phase B: per-wave softmax, all in registers ----
    float m0 = -INFINITY, m1 = -INFINITY, m2 = -INFINITY, m3 = -INFINITY;
#pragma unroll
    for (int i = 0; i < 8; ++i) {
        m0 = fmaxf(m0, sreg[i].x); m1 = fmaxf(m1, sreg[i].y);
        m2 = fmaxf(m2, sreg[i].z); m3 = fmaxf(m3, sreg[i].w);
    }
#pragma unroll
    for (int msk = 8; msk <= 32; msk <<= 1) {
        m0 = fmaxf(m0, __shfl_xor(m0, msk, 64));
        m1 = fmaxf(m1, __shfl_xor(m1, msk, 64));
        m2 = fmaxf(m2, __shfl_xor(m2, msk, 64));
        m3 = fmaxf(m3, __shfl_xor(m3, msk, 64));
    }
    // active wave => at least one finite score => m* finite
    float s0 = 0.f, s1 = 0.f, s2 = 0.f, s3 = 0.f;
#pragma unroll
    for (int i = 0; i < 8; ++i) {
        const float e0 = __expf(sreg[i].x - m0);
        const float e1 = __expf(sreg[i].y - m1);
        const float e2 = __expf(sreg[i].z - m2);
        const float e3 = __expf(sreg[i].w - m3);
        sreg[i] = make_float4(e0, e1, e2, e3);
        s0 += e0; s1 += e1; s2 += e2; s3 += e3;
    }
#pragma unroll
    for (int msk = 8; msk <= 32; msk <<= 1) {
        s0 += __shfl_xor(s0, msk, 64);
        s1 += __shfl_xor(s1, msk, 64);
        s2 += __shfl_xor(s2, msk, 64);
        s3 += __shfl_xor(s3, msk, 64);
    }
    if (lane == 0) {
        *(float4*)(wp)     = make_float4(m0, m1, m2, m3);
        *(float4*)(wp + 4) = make_float4(s0, s1, s2, s3);
    }

    // hand p to Phase C lanes via this wave's LDS strip (rows i*8+lr)
    if (lc == 0) {
#pragma unroll
        for (int i = 0; i < 8; ++i)
            *(float4*)&sc[w][i * 8 + lr][0] = sreg[i];
    }
    // intra-wave DS write -> read ordering (rule-18 pattern, no s_barrier)
    asm volatile("s_waitcnt lgkmcnt(0)" ::: "memory");
    __builtin_amdgcn_sched_barrier(0);

    // ---- Phase C: P*V (2 rows per iter via lane halves, depth-1 pipe) ----
    {
        float4 o0 = {0,0,0,0}, o1 = {0,0,0,0}, o2 = {0,0,0,0}, o3 = {0,0,0,0};
        for (int i = 0; i < itC; ++i) {
            float4 nv = {0,0,0,0};
            if (i + 1 < itC) {
                const int rn = 2 * (i + 1) + half;
                const float* vr = (rn == newrow)
                    ? (vnew_h + dd)
                    : (vb + (size_t)(sb_base + rn) * (HKV * D_) + dd);
                nv = ntload4(vr);
            }
            const int r = 2 * i + half;   // overshoot past valid ok: p = 0
            const float4 vv = cv;
            const float4 pp = *(const float4*)&sc[w][r][0];
            o0.x += pp.x * vv.x; o0.y += pp.x * vv.y; o0.z += pp.x * vv.z; o0.w += pp.x * vv.w;
            o1.x += pp.y * vv.x; o1.y += pp.y * vv.y; o1.z += pp.y * vv.z; o1.w += pp.y * vv.w;
            o2.x += pp.z * vv.x; o2.y += pp.z * vv.y; o2.z += pp.z * vv.z; o2.w += pp.z * vv.w;
            o3.x += pp.w * vv.x; o3.y += pp.w * vv.y; o3.z += pp.w * vv.z; o3.w += pp.w * vv.w;
            cv = nv;
        }
        o0.x += __shfl_xor(o0.x, 32, 64); o0.y += __shfl_xor(o0.y, 32, 64);
        o0.z += __shfl_xor(o0.z, 32, 64); o0.w += __shfl_xor(o0.w, 32, 64);
        o1.x += __shfl_xor(o1.x, 32, 64); o1.y += __shfl_xor(o1.y, 32, 64);
        o1.z += __shfl_xor(o1.z, 32, 64); o1.w += __shfl_xor(o1.w, 32, 64);
        o2.x += __shfl_xor(o2.x, 32, 64); o2.y += __shfl_xor(o2.y, 32, 64);
        o2.z += __shfl_xor(o2.z, 32, 64); o2.w += __shfl_xor(o2.w, 32, 64);
        o3.x += __shfl_xor(o3.x, 32, 64); o3.y += __shfl_xor(o3.y, 32, 64);
        o3.z += __shfl_xor(o3.z, 32, 64); o3.w += __shfl_xor(o3.w, 32, 64);
        if (half == 0) {
            *(float4*)(wp + 8 + 0*D_ + dd) = o0;
            *(float4*)(wp + 8 + 1*D_ + dd) = o1;
            *(float4*)(wp + 8 + 2*D_ + dd) = o2;
            *(float4*)(wp + 8 + 3*D_ + dd) = o3;
        }
    }
}

// ---------------------------------------------------------------------------
// Kernel 2: combine 32 wave-partials per (b, kv_head), normalize, store.
// Empty partials carry m = -inf and poison l/o; NaN-safe selects skip them.
// ---------------------------------------------------------------------------
__global__ __launch_bounds__(128) void combine_attn(
    const float* __restrict__ ws, float* __restrict__ out)
{
    const int bk = blockIdx.x;
    const int b  = bk >> 3;
    const int kh = bk & 7;
    const int d  = threadIdx.x;
    const float* base = ws + (size_t)bk * NPART * PART_STRIDE;

#pragma unroll
    for (int g = 0; g < G_; ++g) {
        float M = -INFINITY;
#pragma unroll
        for (int c = 0; c < NPART; ++c)
            M = fmaxf(M, base[c * PART_STRIDE + g]);
        float sarr[NPART];
        float L = 0.f;
#pragma unroll
        for (int c = 0; c < NPART; ++c) {
            const float mc = base[c * PART_STRIDE + g];
            const float s  = (mc == -INFINITY) ? 0.f : __expf(mc - M);
            sarr[c] = s;
            const float lv = base[c * PART_STRIDE + 4 + g];
            L += (s == 0.f) ? 0.f : s * lv;
        }
        float o = 0.f;
#pragma unroll
        for (int c = 0; c < NPART; ++c) {
            const float ov = base[c * PART_STRIDE + 8 + g * D_ + d];
            o += (sarr[c] == 0.f) ? 0.f : sarr[c] * ov;
        }
        out[(size_t)b * (H_ * D_) + (size_t)(kh * G_ + g) * D_ + d] = o / L;
    }
}

extern "C" void kernel_launch(void* const* d_in, const int* in_sizes, int n_in,
                              void* d_out, int out_size, void* d_ws, size_t ws_size,
                              hipStream_t stream) {
    const float* query = (const float*)d_in[0];
    const float* knew  = (const float*)d_in[1];
    const float* vnew  = (const float*)d_in[2];
    const float* kcache = (const float*)d_in[3];   // never written
    const float* vcache = (const float*)d_in[4];   // never written
    const int* block_list = (const int*)d_in[5];
    const int* bidx = (const int*)d_in[7];
    const int* boff = (const int*)d_in[8];
    // d_in[9] (block_bias) is not read: active rows have bias == 0.0,
    // inactive rows get score -inf directly.
    float* out = (float*)d_out;
    float* ws  = (float*)d_ws;   // needs B*HKV*NPART*520*4 = 17.0 MB

    hipLaunchKernelGGL(partial_attn, dim3(B_ * HKV * NCH), dim3(256), 0, stream,
                       query, knew, vnew, kcache, vcache, block_list,
                       bidx, boff, ws);
    hipLaunchKernelGGL(combine_attn, dim3(B_ * HKV), dim3(128), 0, stream,
                       ws, out);
}

// Round 4
// 553.113 us; speedup vs baseline: 1.0733x; 1.0733x over previous
//
#include <hip/hip_runtime.h>
#include <math.h>

#define B_   32
#define H_   32
#define HKV  8
#define G_   4
#define D_   128
#define BS_  128
#define NB_  16
#define CH_  2             // cache blocks per chunk
#define NCH  (NB_ / CH_)   // 8 chunks per sequence
#define CP_  (CH_ * BS_)   // 256 positions per chunk
#define PART_STRIDE (G_ + G_ + G_ * D_)   // m[4] l[4] o[4][128] = 520 floats

typedef float v4f __attribute__((ext_vector_type(4)));

__device__ __forceinline__ float dot4(const float4 a, const float4 b) {
    return a.x * b.x + a.y * b.y + a.z * b.z + a.w * b.w;
}

// Non-temporal 16B load: K/V are streamed exactly once, keep them out of L2/L3
// so the ws partials (re-read by combine_attn) stay cached.
__device__ __forceinline__ float4 ntload4(const float* p) {
    v4f t = __builtin_nontemporal_load((const v4f*)p);
    return make_float4(t.x, t.y, t.z, t.w);
}

// ---------------------------------------------------------------------------
// Kernel 1: partial attention over one chunk (2 cache blocks = 256 positions)
// of one (b, kv_head). Grid 2048 = B*HKV*NCH, 256 threads (4 waves).
// Wave w owns chunk-local positions [64w, 64w+64).
// Phase A: 8 lanes per K row, 4 float4 loads/lane, 3-level xor reduce,
//          depth-1 software pipeline (64 B/lane in flight).
// Phase C: P*V with V loads grouped 4 row-pairs at a time (64 B/lane in
//          flight, depth-1 across groups) — 8 latency-exposed waits per wave
//          instead of 32. Accumulation order identical to the ungrouped loop.
// Bias is analytic: active rows (pos < ctx) have bias == 0.0, inactive rows
// keep the -inf score init — block_bias is never read (bit-exact).
//
// INPUT-PURE: caches never written; the new decode token's K/V row is
// substituted in-register at row ctx-1.
// ---------------------------------------------------------------------------
__global__ __launch_bounds__(256) void partial_attn(
    const float* __restrict__ query,
    const float* __restrict__ knew,
    const float* __restrict__ vnew,
    const float* __restrict__ kcache,
    const float* __restrict__ vcache,
    const int* __restrict__ block_list,
    const int* __restrict__ bidx, const int* __restrict__ boff,
    float* __restrict__ ws)
{
    __shared__ float q_s[G_][D_];        // 2 KB
    __shared__ float sc[CP_][G_];        // 4 KB scores -> p
    __shared__ float red[4][G_];
    __shared__ float mg[G_];
    __shared__ float dn[G_];
    __shared__ float ob[4][G_][D_];      // 8 KB per-wave o partials

    const int tid  = threadIdx.x;
    const int w    = tid >> 6;
    const int lane = tid & 63;
    const int bx   = blockIdx.x;
    const int ch   = bx & (NCH - 1);
    const int kh   = (bx >> 3) & 7;
    const int b    = bx >> 6;
    constexpr float SCALE = 0.08838834764831845f;  // 1/sqrt(128)

    // ---- recover ctx: which seq-local block holds the new token ----
    const int my_bi = bidx[b];
    int jstar = 0;
#pragma unroll
    for (int jj = 0; jj < NB_; ++jj)
        if (block_list[b * NB_ + jj] == my_bi) jstar = jj;
    const int ctx = jstar * BS_ + boff[b] + 1;   // tokens in this sequence

    float* wp = ws + (size_t)bx * PART_STRIDE;
    const int chunk_start = ch * CP_;
    if (ctx <= chunk_start) {                    // fully masked chunk
        if (tid < 4) wp[tid] = -INFINITY;        // combine scales by 0
        return;
    }

    // ---- load scaled query; init scores to -inf ----
    for (int i = tid; i < G_ * D_; i += 256) {
        const int g = i >> 7, d = i & 127;
        q_s[g][d] = query[(size_t)b * (H_ * D_) + (size_t)(kh * G_ + g) * D_ + d] * SCALE;
    }
    *(float4*)&sc[tid][0] = make_float4(-INFINITY, -INFINITY, -INFINITY, -INFINITY);
    __syncthreads();

    // wave -> block and 64-row window
    const int jl = w >> 1;
    const int j  = ch * CH_ + jl;
    const int tb = b * NB_ + j;
    const int cb = block_list[tb];
    const int sb_base = (w & 1) * 64;
    const float* kb   = kcache + ((size_t)cb * BS_ * HKV + kh) * D_;
    const float* vb   = vcache + ((size_t)cb * BS_ * HKV + kh) * D_;

    const int wave_start = j * BS_ + sb_base;                 // abs pos of row 0
    const int valid_rows = min(64, max(0, ctx - wave_start)); // rows to process
    const int newrow = (ctx - 1) - wave_start;                // row of new token (may be OOR)
    const float* knew_h = knew + ((size_t)b * HKV + kh) * D_; // new-token K row for this head
    const float* vnew_h = vnew + ((size_t)b * HKV + kh) * D_; // new-token V row

    // ---- Phase A: scores (8 lanes per row, 3-level reduce, depth-1 pipe) ----
    {
        const int l3 = lane >> 3;    // row subgroup 0..7
        const int l8 = lane & 7;     // dim subgroup
        const int doff = l8 * 4;
        const float4 q00 = *(const float4*)&q_s[0][doff];
        const float4 q01 = *(const float4*)&q_s[0][32 + doff];
        const float4 q02 = *(const float4*)&q_s[0][64 + doff];
        const float4 q03 = *(const float4*)&q_s[0][96 + doff];
        const float4 q10 = *(const float4*)&q_s[1][doff];
        const float4 q11 = *(const float4*)&q_s[1][32 + doff];
        const float4 q12 = *(const float4*)&q_s[1][64 + doff];
        const float4 q13 = *(const float4*)&q_s[1][96 + doff];
        const float4 q20 = *(const float4*)&q_s[2][doff];
        const float4 q21 = *(const float4*)&q_s[2][32 + doff];
        const float4 q22 = *(const float4*)&q_s[2][64 + doff];
        const float4 q23 = *(const float4*)&q_s[2][96 + doff];
        const float4 q30 = *(const float4*)&q_s[3][doff];
        const float4 q31 = *(const float4*)&q_s[3][32 + doff];
        const float4 q32 = *(const float4*)&q_s[3][64 + doff];
        const float4 q33 = *(const float4*)&q_s[3][96 + doff];

        const int itA = (valid_rows + 7) >> 3;

        float4 c0 = {0,0,0,0}, c1 = {0,0,0,0}, c2 = {0,0,0,0}, c3 = {0,0,0,0};
        {   // prologue: load iteration 0
            const int r = l3;
            if (r < valid_rows) {
                const float* kr = (r == newrow)
                    ? (knew_h + doff)
                    : (kb + (size_t)(sb_base + r) * (HKV * D_) + doff);
                c0 = ntload4(kr);
                c1 = ntload4(kr + 32);
                c2 = ntload4(kr + 64);
                c3 = ntload4(kr + 96);
            }
        }
        for (int i = 0; i < itA; ++i) {
            // issue next iteration's loads first (overlap with this compute)
            float4 n0 = {0,0,0,0}, n1 = {0,0,0,0}, n2 = {0,0,0,0}, n3 = {0,0,0,0};
            const int rn = ((i + 1) << 3) + l3;
            if (rn < valid_rows) {   // false automatically when i+1 == itA
                const float* kr = (rn == newrow)
                    ? (knew_h + doff)
                    : (kb + (size_t)(sb_base + rn) * (HKV * D_) + doff);
                n0 = ntload4(kr);
                n1 = ntload4(kr + 32);
                n2 = ntload4(kr + 64);
                n3 = ntload4(kr + 96);
            }

            const int r = (i << 3) + l3;
            float d0 = dot4(c0,q00) + dot4(c1,q01) + dot4(c2,q02) + dot4(c3,q03);
            float d1 = dot4(c0,q10) + dot4(c1,q11) + dot4(c2,q12) + dot4(c3,q13);
            float d2 = dot4(c0,q20) + dot4(c1,q21) + dot4(c2,q22) + dot4(c3,q23);
            float d3 = dot4(c0,q30) + dot4(c1,q31) + dot4(c2,q32) + dot4(c3,q33);
#pragma unroll
            for (int m = 4; m >= 1; m >>= 1) {
                d0 += __shfl_xor(d0, m, 64);
                d1 += __shfl_xor(d1, m, 64);
                d2 += __shfl_xor(d2, m, 64);
                d3 += __shfl_xor(d3, m, 64);
            }
            if (l8 == 0 && r < valid_rows) {   // bias == 0 for active rows
                *(float4*)&sc[(w << 6) + r][0] = make_float4(d0, d1, d2, d3);
            }
            c0 = n0; c1 = n1; c2 = n2; c3 = n3;
        }
    }
    __syncthreads();

    // ---- Phase B: local softmax over 256 positions ----
    {
        const int g = tid & 3;
        const int u = tid >> 2;
        float m = -INFINITY;
#pragma unroll
        for (int i = 0; i < 4; ++i) m = fmaxf(m, sc[u + 64 * i][g]);
#pragma unroll
        for (int msk = 4; msk <= 32; msk <<= 1) m = fmaxf(m, __shfl_xor(m, msk, 64));
        if (lane < 4) red[w][lane] = m;
        __syncthreads();
        if (tid < 4)
            mg[tid] = fmaxf(fmaxf(red[0][tid], red[1][tid]),
                            fmaxf(red[2][tid], red[3][tid]));
        __syncthreads();

        const float gmr = mg[g];
        const float gm  = (gmr == -INFINITY) ? 0.f : gmr;
        float acc = 0.f;
#pragma unroll
        for (int i = 0; i < 4; ++i) {
            const float p = __expf(sc[u + 64 * i][g] - gm);
            sc[u + 64 * i][g] = p;
            acc += p;
        }
#pragma unroll
        for (int msk = 4; msk <= 32; msk <<= 1) acc += __shfl_xor(acc, msk, 64);
        if (lane < 4) red[w][lane] = acc;
        __syncthreads();
        if (tid < 4) dn[tid] = red[0][tid] + red[1][tid] + red[2][tid] + red[3][tid];
        __syncthreads();
    }

    // ---- Phase C: P*V, V loads grouped 4 row-pairs per step (depth-1) ----
    // Same accumulation order as the pair-at-a-time loop; rows past
    // valid_rows contribute p = 0 and their loads are in-bounds (cache
    // blocks hold 128 rows), so the hot loop has no masking.
    {
        const int half = lane >> 5;
        const int l5   = lane & 31;
        const int dd   = l5 * 4;
        auto vrow = [&](int rr) -> const float* {
            return (rr == newrow) ? (vnew_h + dd)
                                  : (vb + (size_t)(sb_base + rr) * (HKV * D_) + dd);
        };
        float4 o0 = {0,0,0,0}, o1 = {0,0,0,0}, o2 = {0,0,0,0}, o3 = {0,0,0,0};
        const int itC = min(32, (valid_rows + 1) >> 1);   // row-pairs
        const int ng  = (itC + 3) >> 2;                   // groups of 4 pairs

        float4 cv0 = {0,0,0,0}, cv1 = {0,0,0,0}, cv2 = {0,0,0,0}, cv3 = {0,0,0,0};
        if (ng > 0) {   // prologue: group 0 (rows half, 2+half, 4+half, 6+half)
            cv0 = ntload4(vrow(half));
            cv1 = ntload4(vrow(2 + half));
            cv2 = ntload4(vrow(4 + half));
            cv3 = ntload4(vrow(6 + half));
        }
        for (int gi = 0; gi < ng; ++gi) {
            float4 nv0 = {0,0,0,0}, nv1 = {0,0,0,0}, nv2 = {0,0,0,0}, nv3 = {0,0,0,0};
            if (gi + 1 < ng) {
                const int rb = 8 * (gi + 1);
                nv0 = ntload4(vrow(rb + half));
                nv1 = ntload4(vrow(rb + 2 + half));
                nv2 = ntload4(vrow(rb + 4 + half));
                nv3 = ntload4(vrow(rb + 6 + half));
            }
            const int rb = 8 * gi;
            float4 vv[4] = {cv0, cv1, cv2, cv3};
#pragma unroll
            for (int u = 0; u < 4; ++u) {
                const int r = rb + 2 * u + half;          // <= 63 always
                const float4 pp = *(const float4*)&sc[(w << 6) + r][0];
                const float4 v2 = vv[u];
                o0.x += pp.x * v2.x; o0.y += pp.x * v2.y; o0.z += pp.x * v2.z; o0.w += pp.x * v2.w;
                o1.x += pp.y * v2.x; o1.y += pp.y * v2.y; o1.z += pp.y * v2.z; o1.w += pp.y * v2.w;
                o2.x += pp.z * v2.x; o2.y += pp.z * v2.y; o2.z += pp.z * v2.z; o2.w += pp.z * v2.w;
                o3.x += pp.w * v2.x; o3.y += pp.w * v2.y; o3.z += pp.w * v2.z; o3.w += pp.w * v2.w;
            }
            cv0 = nv0; cv1 = nv1; cv2 = nv2; cv3 = nv3;
        }
        o0.x += __shfl_xor(o0.x, 32, 64); o0.y += __shfl_xor(o0.y, 32, 64);
        o0.z += __shfl_xor(o0.z, 32, 64); o0.w += __shfl_xor(o0.w, 32, 64);
        o1.x += __shfl_xor(o1.x, 32, 64); o1.y += __shfl_xor(o1.y, 32, 64);
        o1.z += __shfl_xor(o1.z, 32, 64); o1.w += __shfl_xor(o1.w, 32, 64);
        o2.x += __shfl_xor(o2.x, 32, 64); o2.y += __shfl_xor(o2.y, 32, 64);
        o2.z += __shfl_xor(o2.z, 32, 64); o2.w += __shfl_xor(o2.w, 32, 64);
        o3.x += __shfl_xor(o3.x, 32, 64); o3.y += __shfl_xor(o3.y, 32, 64);
        o3.z += __shfl_xor(o3.z, 32, 64); o3.w += __shfl_xor(o3.w, 32, 64);
        if (half == 0) {
            *(float4*)&ob[w][0][dd] = o0;
            *(float4*)&ob[w][1][dd] = o1;
            *(float4*)&ob[w][2][dd] = o2;
            *(float4*)&ob[w][3][dd] = o3;
        }
    }
    __syncthreads();

    // ---- write partial (m, l, o) ----
    if (tid < 4) { wp[tid] = mg[tid]; wp[4 + tid] = dn[tid]; }
    for (int e = tid; e < G_ * D_; e += 256) {
        const int g = e >> 7, d = e & 127;
        wp[8 + e] = ob[0][g][d] + ob[1][g][d] + ob[2][g][d] + ob[3][g][d];
    }
}

// ---------------------------------------------------------------------------
// Kernel 2: combine 8 chunk-partials per (b, kv_head), normalize, store.
// ---------------------------------------------------------------------------
__global__ __launch_bounds__(128) void combine_attn(
    const float* __restrict__ ws, float* __restrict__ out)
{
    const int bk = blockIdx.x;
    const int b  = bk >> 3;
    const int kh = bk & 7;
    const int d  = threadIdx.x;
    const float* base = ws + (size_t)bk * NCH * PART_STRIDE;

#pragma unroll
    for (int g = 0; g < G_; ++g) {
        float M = -INFINITY;
#pragma unroll
        for (int c = 0; c < NCH; ++c)
            M = fmaxf(M, base[c * PART_STRIDE + g]);
        float scales[NCH];
        float L = 0.f;
#pragma unroll
        for (int c = 0; c < NCH; ++c) {
            const float mc = base[c * PART_STRIDE + g];
            const float s  = (mc == -INFINITY) ? 0.f : __expf(mc - M);
            scales[c] = s;
            L += s * base[c * PART_STRIDE + 4 + g];
        }
        float o = 0.f;
#pragma unroll
        for (int c = 0; c < NCH; ++c)
            o += scales[c] * base[c * PART_STRIDE + 8 + g * D_ + d];
        out[(size_t)b * (H_ * D_) + (size_t)(kh * G_ + g) * D_ + d] = o / L;
    }
}

extern "C" void kernel_launch(void* const* d_in, const int* in_sizes, int n_in,
                              void* d_out, int out_size, void* d_ws, size_t ws_size,
                              hipStream_t stream) {
    const float* query = (const float*)d_in[0];
    const float* knew  = (const float*)d_in[1];
    const float* vnew  = (const float*)d_in[2];
    const float* kcache = (const float*)d_in[3];   // never written
    const float* vcache = (const float*)d_in[4];   // never written
    const int* block_list = (const int*)d_in[5];
    const int* bidx = (const int*)d_in[7];
    const int* boff = (const int*)d_in[8];
    // d_in[9] (block_bias) is not read: active rows have bias == 0.0,
    // inactive rows get score -inf directly.
    float* out = (float*)d_out;
    float* ws  = (float*)d_ws;   // needs B*HKV*NCH*520*4 = 4.26 MB

    hipLaunchKernelGGL(partial_attn, dim3(B_ * HKV * NCH), dim3(256), 0, stream,
                       query, knew, vnew, kcache, vcache, block_list,
                       bidx, boff, ws);
    hipLaunchKernelGGL(combine_attn, dim3(B_ * HKV), dim3(128), 0, stream,
                       ws, out);
}